// Round 7
// baseline (110.769 us; speedup 1.0000x reference)
//
#include <hip/hip_runtime.h>
#include <hip/hip_bf16.h>

// SNNDecode: z = x @ W^T  (einsum 'bsh,oh->sbo'), then linear LI scan over seq.
//   v_t = v_{t-1} + a*(i_{t-1} - v_{t-1});  i_t = (1-b)*i_{t-1} + z_t;  out[t]=v_t
// d_out = [voltages (2048*64*128)] ++ [v_f (8192)] ++ [i_f (8192)]  (fp32)
//
// Round 7: z NEVER hits global memory. Each gemm block computes its tile's
// 128-step zero-state voltage trace in LDS (two 64-step half-scans + rank-2
// closed-form splice) and writes v_local to Out; publishes per-tile end-states.
// k_tilecombine (tiny) -> per-tile in-states + finals. k_fix streams a rank-2
// correction Out[t] += alpha_j*v_in + beta_j*i_in over tiles 1..15. k_emit is
// DELETED along with its 64MB Z re-read and 129MB prefix traffic.
// ws layout (floats): [0) vT[16][8192] | iT[16][8192] | vin[16][8192] |
// iin[16][8192] == 2 MiB, then bf16 W (128 KiB).

typedef __attribute__((ext_vector_type(4))) float    f4;
typedef __attribute__((ext_vector_type(8))) short    s8;
typedef __attribute__((ext_vector_type(4))) unsigned u4;

#define SEQ    2048
#define HID    512
#define CHAINS 8192          // batch(64) * out(128)
#define VOLT   16777216      // SEQ * CHAINS
#define NT     16            // t-tiles per batch row (2048/128)

__device__ __forceinline__ float clamp01(float x) { return fminf(fmaxf(x, 0.f), 1.f); }

// packed fp32x2 -> bf16x2 (RNE) as one u32; compiler emits v_cvt_pk_bf16_f32
__device__ __forceinline__ unsigned pkbf(float x, float y) {
  float2 t; t.x = x; t.y = y;
  union { __hip_bfloat162 h; unsigned u; } c;
  c.h = __float22bfloat162_rn(t);
  return c.u;
}

// fp32 -> bf16 bits (RNE), scalar (wconv only)
__device__ __forceinline__ short f2bf(float f) {
  union { float f; unsigned u; } c; c.f = f;
  unsigned u = c.u;
  unsigned r = (u + 0x7fffu + ((u >> 16) & 1u)) >> 16;
  return (short)r;
}

// LDS swizzle (ushort-index units): XOR row-low-bits into k bits 3..5 so both
// ds_write_b128 staging and ds_read_b128 fragment reads hit all banks evenly.
__device__ __forceinline__ int swz(int row, int k) {
  return (row * 64 + k) ^ ((row & 7) << 3);
}

// ---------------- Phase 0: W (fp32 [128][512]) -> bf16 in ws ---------------
__global__ __launch_bounds__(256) void k_wconv(const float* __restrict__ W,
                                               unsigned short* __restrict__ Wb) {
  const int i = blockIdx.x * 256 + threadIdx.x;   // 8192 threads, 8 elems each
  const f4 lo = ((const f4*)W)[2 * i];
  const f4 hi = ((const f4*)W)[2 * i + 1];
  s8 v;
#pragma unroll
  for (int j = 0; j < 4; ++j) { v[j] = f2bf(lo[j]); v[j + 4] = f2bf(hi[j]); }
  ((s8*)Wb)[i] = v;
}

// ---------------- Phase 1: GEMM tile -> in-LDS full 128-step local scan ----
// Writes v_local (tile-local zero-state voltages) to Out; z stays in LDS.
__global__ __launch_bounds__(256, 2) void k_gemm(const float* __restrict__ X,
                                                 const unsigned short* __restrict__ Wb,
                                                 float* __restrict__ Out,
                                                 const float* __restrict__ tau_syn,
                                                 const float* __restrict__ tau_mem,
                                                 float* __restrict__ ws) {
  __shared__ __align__(16) char smem[65536];
  __shared__ float vh0[128], ih0[128];       // chunk-0 end states
  short* const AS = (short*)smem;            // [2][128][64] bf16 A tiles (32 KB)
  float* const ZS = (float*)smem;            // [128][128] f32 z tile (aliased)

  const int tid = threadIdx.x;
  const int blk = blockIdx.x;
  const int m0  = blk << 7;          // global row = b*2048 + t
  const int bI  = blk >> 4;          // batch index
  const int jt  = blk & 15;          // t-tile index
  const int t0  = jt << 7;           // t tile base

  const int rbase = tid >> 3;        // 0..31: staging row group
  const int coff  = (tid & 7) << 3;  // staging k offset (8 elems)

  const int lane = tid & 63;
  const int wid  = tid >> 6;
  const int wmb  = (wid >> 1) << 6;  // wave row base: 0/64
  const int wnb  = (wid & 1) << 6;   // wave col base: 0/64
  const int lr   = lane & 15;
  const int lk   = (lane >> 4) << 3;

  const float* pX[4];
#pragma unroll
  for (int c = 0; c < 4; ++c)
    pX[c] = X + (size_t)(m0 + (c << 5) + rbase) * HID + coff;
  const unsigned short* pB[4];
#pragma unroll
  for (int ni = 0; ni < 4; ++ni)
    pB[ni] = Wb + (size_t)(wnb + (ni << 4) + lr) * HID + lk;

  f4 acc[4][4];
#pragma unroll
  for (int mi = 0; mi < 4; ++mi)
#pragma unroll
    for (int ni = 0; ni < 4; ++ni) acc[mi][ni] = (f4){0.f, 0.f, 0.f, 0.f};

  // A register prefetch: ring of 3 (2 steps ahead); static indices via unroll.
  f4 xa[3][4][2];
#pragma unroll
  for (int c = 0; c < 4; ++c) {
    xa[0][c][0] = *(const f4*)(pX[c]);
    xa[0][c][1] = *(const f4*)(pX[c] + 4);
    xa[1][c][0] = *(const f4*)(pX[c] + 64);
    xa[1][c][1] = *(const f4*)(pX[c] + 68);
  }

#pragma unroll
  for (int ks = 0; ks < 8; ++ks) {
    const int cur = ks % 3;
    short* const Ac = AS + ((ks & 1) << 13);
    // Stage current A tile into LDS (consumes xa[cur] = oldest outstanding
    // loads; deeper prefetch stays in flight through the wait).
#pragma unroll
    for (int c = 0; c < 4; ++c) {
      const int row = (c << 5) + rbase;
      u4 va;
      va[0] = pkbf(xa[cur][c][0][0], xa[cur][c][0][1]);
      va[1] = pkbf(xa[cur][c][0][2], xa[cur][c][0][3]);
      va[2] = pkbf(xa[cur][c][1][0], xa[cur][c][1][1]);
      va[3] = pkbf(xa[cur][c][1][2], xa[cur][c][1][3]);
      *(u4*)&Ac[swz(row, coff)] = va;
    }
    __syncthreads();
    // B fragments for this step (L2-resident W), issued BEFORE the deep xa
    // prefetch so their vmcnt-consume (in-order) doesn't drain the xa loads.
    s8 bg[2][4];
#pragma unroll
    for (int kk = 0; kk < 2; ++kk)
#pragma unroll
      for (int ni = 0; ni < 4; ++ni)
        bg[kk][ni] = *(const s8*)(pB[ni] + (ks << 6) + (kk << 5));
    // Deep prefetch: A tile for step ks+2.
    if (ks < 6) {
      const int k0 = (ks + 2) << 6;
      const int nxt = (ks + 2) % 3;
#pragma unroll
      for (int c = 0; c < 4; ++c) {
        xa[nxt][c][0] = *(const f4*)(pX[c] + k0);
        xa[nxt][c][1] = *(const f4*)(pX[c] + k0 + 4);
      }
    }
#pragma unroll
    for (int kk = 0; kk < 2; ++kk) {
      s8 af[4];
#pragma unroll
      for (int mi = 0; mi < 4; ++mi)
        af[mi] = *(const s8*)&Ac[swz(wmb + (mi << 4) + lr, (kk << 5) + lk)];
#pragma unroll
      for (int mi = 0; mi < 4; ++mi)
#pragma unroll
        for (int ni = 0; ni < 4; ++ni)
          acc[mi][ni] = __builtin_amdgcn_mfma_f32_16x16x32_bf16(af[mi], bg[kk][ni],
                                                                acc[mi][ni], 0, 0, 0);
    }
  }

  // ---- Epilogue: park z tile in LDS (aliases dead staging buffer) ----
  __syncthreads();   // all waves done reading AS
  const int rr = (lane >> 4) << 2;
#pragma unroll
  for (int mi = 0; mi < 4; ++mi)
#pragma unroll
    for (int ni = 0; ni < 4; ++ni)
#pragma unroll
      for (int r = 0; r < 4; ++r)
        ZS[(wmb + (mi << 4) + rr + r) * 128 + wnb + (ni << 4) + lr] = acc[mi][ni][r];
  __syncthreads();

  const float a  = 0.001f * clamp01(tau_mem[0]);
  const float bb = 0.001f * clamp01(tau_syn[0]);
  const float ea = 1.f - a, eb = 1.f - bb;
  const int h = tid >> 7, col = tid & 127;

  // (b1) half-scan: zero-state over 64 steps, v_local overwrites z in place.
  {
    float* zc = ZS + ((h << 6) * 128) + col;
    float v = 0.f, ii = 0.f;
#pragma unroll 8
    for (int j = 0; j < 64; ++j) {
      const float z = zc[j * 128];          // bank=col&31: 2-way (free)
      v  = v + a * (ii - v);
      zc[j * 128] = v;
      ii = eb * ii + z;
    }
    if (h == 0) { vh0[col] = v; ih0[col] = ii; }
    __syncthreads();
    // (b2) splice half 1 onto half 0: Dv_j = alpha_j*v0 + beta_j*i0 (rank-2),
    // alpha/beta by the same P/Q recurrence as the verified combine.
    if (h == 1) {
      const float v0 = vh0[col], i0 = ih0[col];
      float al = 1.f, be = 0.f, ep = 1.f;
      float* zc1 = ZS + (64 * 128) + col;
      for (int j = 0; j < 64; ++j) {
        const float aln = al * ea;
        be = al * a + be * eb;               // beta_{j+1}
        al = aln;                            // alpha_{j+1}
        ep *= eb;                            // eb^{j+1}
        zc1[j * 128] += al * v0 + be * i0;
      }
      // tile end-state (zero-state over 128 steps): publish for combine
      const float vE = v + al * v0 + be * i0;
      const float iE = ii + ep * i0;
      ws[jt * CHAINS + (bI << 7) + col]                = vE;   // vT
      ws[NT * CHAINS + jt * CHAINS + (bI << 7) + col]  = iE;   // iT
    }
  }
  __syncthreads();

  // stream v_local tile to Out: f4, 512B-contiguous per 32-lane half
  {
    float* const Orow = Out + (size_t)t0 * 8192 + (bI << 7);
#pragma unroll
    for (int i = 0; i < 16; ++i) {
      const int idx  = (i << 8) + tid;
      const int toff = idx >> 5;
      const int c4   = idx & 31;
      *(f4*)(Orow + (size_t)toff * 8192 + (c4 << 2)) = *(const f4*)&ZS[toff * 128 + (c4 << 2)];
    }
  }
}

// ---------------- Phase 2: combine tile end-states -> per-tile in-states +
// finals. 2048 f4 chain-groups, 16 dependent L2 loads each. Tiny.
__global__ __launch_bounds__(256) void k_tilecombine(const float* __restrict__ tau_syn,
                                                     const float* __restrict__ tau_mem,
                                                     float* __restrict__ Out,
                                                     float* __restrict__ ws) {
  const int cg = blockIdx.x * 256 + threadIdx.x;   // 0..2047
  const float a  = 0.001f * clamp01(tau_mem[0]);
  const float bb = 0.001f * clamp01(tau_syn[0]);
  const float ea = 1.f - a, eb = 1.f - bb;
  float P = 1.f, Q = 0.f, R = 1.f;                 // M^128 first row [P,Q]; R=eb^128
#pragma unroll
  for (int j = 0; j < 128; ++j) { const float Pn = P * ea; Q = P * a + Q * eb; P = Pn; R *= eb; }

  const f4* vT = (const f4*)ws;                    // [16][2048]
  const f4* iT = vT + NT * 2048;
  f4* vin = (f4*)ws + 2 * NT * 2048;
  f4* iin = vin + NT * 2048;
  f4 sv = (f4){0.f, 0.f, 0.f, 0.f}, si = (f4){0.f, 0.f, 0.f, 0.f};
  for (int p = 0; p < NT; ++p) {
    vin[p * 2048 + cg] = sv;  iin[p * 2048 + cg] = si;   // exclusive prefix
    const f4 Ev = vT[p * 2048 + cg], Ei = iT[p * 2048 + cg];
    const f4 nv = P * sv + Q * si + Ev;
    si = R * si + Ei;
    sv = nv;
  }
  ((f4*)(Out + VOLT))[cg]          = sv;   // v_f
  ((f4*)(Out + VOLT + CHAINS))[cg] = si;   // i_f
}

// ---------------- Phase 3: rank-2 streaming fix for tiles 1..15:
// Out[t] += alpha_{j}*v_in[tile] + beta_{j}*i_in[tile], j = (t&127)+1.
__global__ __launch_bounds__(256) void k_fix(const float* __restrict__ tau_syn,
                                             const float* __restrict__ tau_mem,
                                             float* __restrict__ Out,
                                             const float* __restrict__ ws) {
  __shared__ float tA[128], tB[128];
  const int tid = threadIdx.x;
  if (tid == 0) {
    const float a  = 0.001f * clamp01(tau_mem[0]);
    const float bb = 0.001f * clamp01(tau_syn[0]);
    const float ea = 1.f - a, eb = 1.f - bb;
    float al = 1.f, be = 0.f, ep = 1.f;
    for (int j = 0; j < 128; ++j) {
      const float aln = al * ea;
      be = al * a + be * eb;
      al = aln;
      ep *= eb;
      tA[j] = al; tB[j] = be;
    }
  }
  __syncthreads();
  const f4* vin = (const f4*)ws + 2 * NT * 2048;   // [16][2048]
  const f4* iin = vin + NT * 2048;
  f4* o4 = (f4*)Out;
  const int N = 15 << 18;                          // tiles 1..15, f4 units
  for (int g = blockIdx.x * 256 + tid; g < N; g += 2048 * 256) {
    const int tile = 1 + (g >> 18);
    const int r    = g & ((1 << 18) - 1);
    const int j    = r >> 11;                      // t-offset 0..127 (= j-1)
    const int c4   = r & 2047;
    const f4 vi = vin[tile * 2048 + c4];
    const f4 ij = iin[tile * 2048 + c4];
    const float A = tA[j], B = tB[j];
    const size_t t = ((size_t)((tile << 7) + j)) * 2048 + c4;
    o4[t] = o4[t] + A * vi + B * ij;
  }
}

extern "C" void kernel_launch(void* const* d_in, const int* in_sizes, int n_in,
                              void* d_out, int out_size, void* d_ws, size_t ws_size,
                              hipStream_t stream) {
  const float* X   = (const float*)d_in[0];  // [64][2048][512]
  const float* W   = (const float*)d_in[1];  // [128][512]
  const float* tsy = (const float*)d_in[2];
  const float* tme = (const float*)d_in[3];
  float* Out = (float*)d_out;
  float* ws  = (float*)d_ws;                 // needs 2 MiB + 128 KiB
  unsigned short* Wb = (unsigned short*)((char*)d_ws + (2u << 20));

  k_wconv<<<32, 256, 0, stream>>>(W, Wb);                         // W -> bf16
  k_gemm<<<1024, 256, 0, stream>>>(X, Wb, Out, tsy, tme, ws);     // v_local + tile states
  k_tilecombine<<<8, 256, 0, stream>>>(tsy, tme, Out, ws);        // in-states + finals
  k_fix<<<2048, 256, 0, stream>>>(tsy, tme, Out, ws);             // rank-2 correction
}